// Round 12
// baseline (2856.896 us; speedup 1.0000x reference)
//
#include <hip/hip_runtime.h>

#define B_   256
#define T_   512
#define IN_  34
#define H_   80
#define L_   10
#define NC_  5
#define G4   320
#define TPB  640        // 80 e-elements x 8 K-slices
#define HP   84         // hist row padded 80 -> 84 f16 (168 B)

typedef _Float16 h2 __attribute__((ext_vector_type(2)));
typedef _Float16 h4 __attribute__((ext_vector_type(4)));

template <int CTRL>
__device__ __forceinline__ float dpp_mov(float v) {
    return __int_as_float(__builtin_amdgcn_update_dpp(0, __float_as_int(v), CTRL, 0xF, 0xF, true));
}
__device__ __forceinline__ unsigned dpp_mov_u(unsigned v, int ctrl_unused) { return v; }
__device__ __forceinline__ h2 bc(unsigned u) { return __builtin_bit_cast(h2, u); }
__device__ __forceinline__ h2 lo2(h4 v) { return __builtin_shufflevector(v, v, 0, 1); }
__device__ __forceinline__ h2 hi2(h4 v) { return __builtin_shufflevector(v, v, 2, 3); }

// w2 layout: uint4 index ((l*10 + n)*640 + tid); dword j = n*4+c encodes gate g=j/10,
// q=j%10: f16 pair (k0, k0+1), k0 = (s<4 ? 20*s : 20*(s-4)) + 2*q, row = g*80+e.
// s<4 -> input-side weights (layer0 zero-padded beyond 34), s>=4 -> W_hh.
__global__ void prep_kernel(const float* __restrict__ Wih0, const float* __restrict__ WihR,
                            const float* __restrict__ Whh,  const float* __restrict__ bih,
                            const float* __restrict__ bhh,
                            unsigned* __restrict__ w2, float* __restrict__ bbuf) {
    int idx = blockIdx.x * 256 + threadIdx.x;          // dword index
    const int ND = L_ * 10 * TPB * 4;                  // 256000 dwords
    if (idx < ND) {
        int tid = (idx >> 2) % TPB;
        int n   = ((idx >> 2) / TPB) % 10;
        int l   = (idx >> 2) / (TPB * 10);
        int j   = n * 4 + (idx & 3);
        int g = j / 10, q = j % 10;
        int e = tid >> 3, s = tid & 7;
        int row = g * H_ + e;
        int k0 = (s < 4 ? 20 * s : 20 * (s - 4)) + 2 * q;
        float w0, w1;
        if (s < 4) {
            if (l == 0) {
                w0 = (k0     < IN_) ? Wih0[row * IN_ + k0]     : 0.f;
                w1 = (k0 + 1 < IN_) ? Wih0[row * IN_ + k0 + 1] : 0.f;
            } else {
                w0 = WihR[((size_t)(l - 1) * G4 + row) * H_ + k0];
                w1 = WihR[((size_t)(l - 1) * G4 + row) * H_ + k0 + 1];
            }
        } else {
            w0 = Whh[((size_t)l * G4 + row) * H_ + k0];
            w1 = Whh[((size_t)l * G4 + row) * H_ + k0 + 1];
        }
        h2 p; p[0] = (_Float16)w0; p[1] = (_Float16)w1;
        w2[idx] = __builtin_bit_cast(unsigned, p);
    }
    if (idx < L_ * G4) bbuf[idx] = bih[idx] + bhh[idx];
}

__global__ __launch_bounds__(TPB, 1) void lstm_stack_kernel(
    const float* __restrict__ x,      // [B,T,34]
    const uint4* __restrict__ w2,     // packed f16x2 weights
    const float* __restrict__ bbuf,   // [10][320]
    const float* __restrict__ fcw,    // [5,80]
    const float* __restrict__ fcb,    // [5]
    float* __restrict__ out)          // [B,5]
{
    const int b   = blockIdx.x;
    const int tid = threadIdx.x;      // 0..639
    const int e   = tid >> 3;         // h element 0..79
    const int s   = tid & 7;          // K slice (0-3: input side, 4-7: hidden side)
    const int sg  = s & 3;            // this lane's gate after distribute: 0=i 1=f 2=g 3=o
    const bool wsel = (s == 1) && ((e & 1) == 0);   // packed h-writer lanes

    // per-lane activation constants: sigm for i/f/o, tanh(x)=2*sigm(2x)-1 for g
    const float mA  = (sg == 2) ? -2.885390082f : -1.442695041f;   // -k*log2(e)
    const float bA  = (sg == 2) ? 2.f : 1.f;
    const float cA0 = (sg == 2) ? -1.f : 0.f;
    const bool  sel1 = (s & 1) != 0;
    const bool  sel2 = (s & 2) != 0;

    __shared__ __align__(16) _Float16 hist[T_][HP];   // 86 KB: x (f16) then h history, padded rows
    __shared__ __align__(16) _Float16 hs[2][H_];      // h(t-1) ping-pong

    // ---- stage x -> f16 hist (zero-pad 34..79; cols 80..83 never read) ----
    for (int j = tid; j < T_ * H_; j += TPB) {
        int t = j / H_, k = j % H_;
        float v = (k < IN_) ? x[((size_t)b * T_ + t) * IN_ + k] : 0.f;
        hist[t][k] = (_Float16)v;
    }

    for (int l = 0; l < L_; ++l) {
        // ---- weights for this layer: 10 coalesced uint4 loads, resident all layer ----
        const uint4* wp = w2 + (size_t)l * 10 * TPB + tid;
        uint4 W0 = wp[0 * TPB], W1 = wp[1 * TPB], W2 = wp[2 * TPB], W3 = wp[3 * TPB], W4 = wp[4 * TPB];
        uint4 W5 = wp[5 * TPB], W6 = wp[6 * TPB], W7 = wp[7 * TPB], W8 = wp[8 * TPB], W9 = wp[9 * TPB];

        const float bi = (s == 0) ? bbuf[l * G4 + 0 * H_ + e] : 0.f;
        const float bf = (s == 0) ? bbuf[l * G4 + 1 * H_ + e] : 0.f;
        const float bg = (s == 0) ? bbuf[l * G4 + 2 * H_ + e] : 0.f;
        const float bo = (s == 0) ? bbuf[l * G4 + 3 * H_ + e] : 0.f;

        if (tid < 40) ((unsigned*)&hs[0][0])[tid] = 0;   // h(-1) = 0 (80 f16)
        __syncthreads();

        float cold = 0.f;
        unsigned hpack = 0;      // packed (h[e],h[e+1]) f16 dword, valid on wsel lanes
        int par = 0;

#pragma unroll 4
        for (int t = 0; t < T_; ++t) {
            // ---- loads first: latency overlaps the write + setup below ----
            const h4* vp = (s < 4) ? (const h4*)(&hist[t][0] + 20 * s)
                                   : (const h4*)(&hs[par][0] + 20 * (s - 4));
            h4 v0 = vp[0], v1 = vp[1], v2 = vp[2], v3 = vp[3], v4 = vp[4];

            // deferred history write (packed dword, conflict-free), safe: t-1 consumed
            if (t && wsel) *(unsigned*)(&hist[t - 1][0] + (e & ~1)) = hpack;

            h2 p0 = lo2(v0), p1 = hi2(v0), p2 = lo2(v1), p3 = hi2(v1), p4 = lo2(v2);
            h2 p5 = hi2(v2), p6 = lo2(v3), p7 = hi2(v3), p8 = lo2(v4), p9 = hi2(v4);

            float aI = bi, aF = bf, aG = bg, aO = bo;
#define D(acc, W, C, P) acc = __builtin_amdgcn_fdot2(bc(W.C), P, acc, false);
            D(aI, W0, x, p0) D(aI, W0, y, p1) D(aI, W0, z, p2) D(aI, W0, w, p3)
            D(aI, W1, x, p4) D(aI, W1, y, p5) D(aI, W1, z, p6) D(aI, W1, w, p7)
            D(aI, W2, x, p8) D(aI, W2, y, p9)
            D(aF, W2, z, p0) D(aF, W2, w, p1)
            D(aF, W3, x, p2) D(aF, W3, y, p3) D(aF, W3, z, p4) D(aF, W3, w, p5)
            D(aF, W4, x, p6) D(aF, W4, y, p7) D(aF, W4, z, p8) D(aF, W4, w, p9)
            D(aG, W5, x, p0) D(aG, W5, y, p1) D(aG, W5, z, p2) D(aG, W5, w, p3)
            D(aG, W6, x, p4) D(aG, W6, y, p5) D(aG, W6, z, p6) D(aG, W6, w, p7)
            D(aG, W7, x, p8) D(aG, W7, y, p9)
            D(aO, W7, z, p0) D(aO, W7, w, p1)
            D(aO, W8, x, p2) D(aO, W8, y, p3) D(aO, W8, z, p4) D(aO, W8, w, p5)
            D(aO, W9, x, p6) D(aO, W9, y, p7) D(aO, W9, z, p8) D(aO, W9, w, p9)
#undef D
            // ---- distribute-reduce: lane s ends with 8-lane total of gate (s&3) ----
            float kI = sel1 ? aF : aI, oI = sel1 ? aI : aF;
            float AIF = kI + dpp_mov<0xB1>(oI);            // xor1 pair-sum of kept gate
            float kG = sel1 ? aO : aG, oG = sel1 ? aG : aO;
            float BGO = kG + dpp_mov<0xB1>(oG);
            float k2v = sel2 ? BGO : AIF, o2 = sel2 ? AIF : BGO;
            float S = k2v + dpp_mov<0x4E>(o2);             // xor2: 4-lane sum of gate s&3
            S = S + dpp_mov<0x1B>(dpp_mov<0x141>(S));      // xor4: 8-lane total

            // ---- this lane's gate activation only ----
            float y   = __builtin_amdgcn_rcpf(1.f + __builtin_amdgcn_exp2f(mA * S));
            float act = __builtin_fmaf(bA, y, cA0);

            // ---- c/h update via quad DPP exchanges ----
            float t2v  = dpp_mov<0x4E>(act);               // act[u^2]: i<-g, f<-o
            float prod = act * t2v;                        // i-lanes: i*g
            float t3v  = dpp_mov<0xB1>(prod);              // f-lanes receive i*g
            float cnew = __builtin_fmaf(act, cold, t3v);   // f-lanes: f*c + i*g
            float th   = __builtin_fmaf(2.f,
                           __builtin_amdgcn_rcpf(1.f + __builtin_amdgcn_exp2f(-2.885390082f * cnew)),
                           -1.f);                          // tanh(cnew)
            float h = t2v * th;                            // f-lanes: o * tanh(c)
            cold = cnew;

            // ---- pack (h[e], h[e+1]) into one dword on wsel lanes (RNE kept) ----
            _Float16 h16 = (_Float16)h;
            unsigned hu = (unsigned)__builtin_bit_cast(unsigned short, h16);
            unsigned hn = (unsigned)__builtin_amdgcn_update_dpp(0, (int)hu, 0x128, 0xF, 0xF, true); // row_ror:8
            hpack = hu | (hn << 16);

            if (wsel) *(unsigned*)(&hs[par ^ 1][0] + (e & ~1)) = hpack;
            __syncthreads();
            par ^= 1;
        }
        if (wsel) *(unsigned*)(&hist[T_ - 1][0] + (e & ~1)) = hpack;   // flush last step
        __syncthreads();
    }

    // ---- fc on final hidden state ----
    if (tid < NC_) {
        float acc = fcb[tid];
#pragma unroll
        for (int j = 0; j < H_; ++j) acc += fcw[tid * H_ + j] * (float)hist[T_ - 1][j];
        out[b * NC_ + tid] = acc;
    }
}

extern "C" void kernel_launch(void* const* d_in, const int* in_sizes, int n_in,
                              void* d_out, int out_size, void* d_ws, size_t ws_size,
                              hipStream_t stream) {
    const float* x    = (const float*)d_in[0];
    const float* Wih0 = (const float*)d_in[1];
    const float* WihR = (const float*)d_in[2];
    const float* Whh  = (const float*)d_in[3];
    const float* bih  = (const float*)d_in[4];
    const float* bhh  = (const float*)d_in[5];
    const float* fcw  = (const float*)d_in[6];
    const float* fcb  = (const float*)d_in[7];

    unsigned* w2 = (unsigned*)d_ws;           // 256000 dwords
    float* bbuf  = (float*)(w2 + 256000);     // 3200 floats

    prep_kernel<<<dim3(1000), dim3(256), 0, stream>>>(
        Wih0, WihR, Whh, bih, bhh, w2, bbuf);

    lstm_stack_kernel<<<dim3(B_), dim3(TPB), 0, stream>>>(
        x, (const uint4*)w2, bbuf, fcw, fcb, (float*)d_out);
}

// Round 14
// 2466.732 us; speedup vs baseline: 1.1582x; 1.1582x over previous
//
#include <hip/hip_runtime.h>

#define B_   256
#define T_   512
#define IN_  34
#define H_   80
#define L_   10
#define NC_  5
#define G4   320
#define TPB  640        // waves 0-4: serial chain (h-side); waves 5-9: xp producers (x-side)
#define HP   84         // hist row padded 80 -> 84 f16
#define LAG  2          // producer lead (timesteps)

typedef _Float16 h2 __attribute__((ext_vector_type(2)));
typedef _Float16 h4 __attribute__((ext_vector_type(4)));

template <int CTRL>
__device__ __forceinline__ float dpp_mov(float v) {
    return __int_as_float(__builtin_amdgcn_update_dpp(0, __float_as_int(v), CTRL, 0xF, 0xF, true));
}
__device__ __forceinline__ h2 bc(unsigned u) { return __builtin_bit_cast(h2, u); }
__device__ __forceinline__ h2 lo2(h4 v) { return __builtin_shufflevector(v, v, 0, 1); }
__device__ __forceinline__ h2 hi2(h4 v) { return __builtin_shufflevector(v, v, 2, 3); }

// Both halves use the same per-lane weight layout: lane = e*4 + q4 owns, for all 4
// gates, the K-slice [20*q4, 20*q4+20) (x-side for w1, h-side for w2) of row g*80+e.
// uint4 index (l*10 + n)*320 + lane; dword j=n*4+c: gate=j/10, q=j%10, pair k=20*q4+2q.
__global__ void prep_kernel(const float* __restrict__ Wih0, const float* __restrict__ WihR,
                            const float* __restrict__ Whh,  const float* __restrict__ bih,
                            const float* __restrict__ bhh,
                            unsigned* __restrict__ w1, unsigned* __restrict__ w2,
                            float* __restrict__ bbuf) {
    int idx = blockIdx.x * 256 + threadIdx.x;          // dword index
    const int ND = L_ * 10 * G4 * 4;                   // 128000 dwords per half
    if (idx < ND) {
        int c    = idx & 3;
        int lane = (idx >> 2) % G4;
        int n    = ((idx >> 2) / G4) % 10;
        int l    = (idx >> 2) / (G4 * 10);
        int j = n * 4 + c;
        int gate = j / 10, q = j % 10;
        int e = lane >> 2, q4 = lane & 3;
        int row = gate * H_ + e;
        int k0 = 20 * q4 + 2 * q;
        float a, b;
        if (l == 0) {
            a = (k0     < IN_) ? Wih0[row * IN_ + k0]     : 0.f;
            b = (k0 + 1 < IN_) ? Wih0[row * IN_ + k0 + 1] : 0.f;
        } else {
            const float* p = WihR + ((size_t)(l - 1) * G4 + row) * H_;
            a = p[k0]; b = p[k0 + 1];
        }
        h2 pa; pa[0] = (_Float16)a; pa[1] = (_Float16)b;
        w1[idx] = __builtin_bit_cast(unsigned, pa);
        const float* ph = Whh + ((size_t)l * G4 + row) * H_;
        h2 pb; pb[0] = (_Float16)ph[k0]; pb[1] = (_Float16)ph[k0 + 1];
        w2[idx] = __builtin_bit_cast(unsigned, pb);
    }
    if (idx < L_ * G4) bbuf[idx] = bih[idx] + bhh[idx];
}

__global__ __launch_bounds__(TPB, 1) void lstm_stack_kernel(
    const float* __restrict__ x,      // [B,T,34]
    const uint4* __restrict__ w1,     // x-side weights (producers)
    const uint4* __restrict__ w2,     // h-side weights (chain)
    const float* __restrict__ bbuf,   // [10][320]
    const float* __restrict__ fcw,    // [5,80]
    const float* __restrict__ fcb,    // [5]
    float* __restrict__ out)          // [B,5]
{
    const int b    = blockIdx.x;
    const int tid  = threadIdx.x;             // 0..639
    const bool isProd = tid >= G4;            // waves 5-9 produce xp
    const int lane = isProd ? tid - G4 : tid; // 0..319
    const int e    = lane >> 2;               // h element 0..79
    const int q4   = lane & 3;                // K-slice id == final gate id (0=i 1=f 2=g 3=o)

    const float mA  = (q4 == 2) ? -2.885390082f : -1.442695041f;
    const float bA  = (q4 == 2) ? 2.f : 1.f;
    const float cA0 = (q4 == 2) ? -1.f : 0.f;
    const bool  sel1 = (q4 & 1) != 0;
    const bool  sel2 = (q4 & 2) != 0;

    __shared__ __align__(16) _Float16 hist[T_][HP];   // 86 KB: x (f16) then h history
    __shared__ __align__(16) float xp[4][4][HP];      // 5.4 KB ring: [slot][gate][e]
    __shared__ __align__(16) _Float16 hs[2][H_];      // h(t-1) ping-pong

    // ---- stage x -> f16 hist (zero-pad 34..79) ----
    for (int j = tid; j < T_ * H_; j += TPB) {
        int t = j / H_, k = j % H_;
        float v = (k < IN_) ? x[((size_t)b * T_ + t) * IN_ + k] : 0.f;
        hist[t][k] = (_Float16)v;
    }

    for (int l = 0; l < L_; ++l) {
        // ---- this lane's 40-dword weight half (proven-resident size) ----
        const uint4* wp = (isProd ? w1 : w2) + (size_t)l * 10 * G4 + lane;
        uint4 W0 = wp[0 * G4], W1 = wp[1 * G4], W2 = wp[2 * G4], W3 = wp[3 * G4], W4 = wp[4 * G4];
        uint4 W5 = wp[5 * G4], W6 = wp[6 * G4], W7 = wp[7 * G4], W8 = wp[8 * G4], W9 = wp[9 * G4];
        const float bias = isProd ? bbuf[l * G4 + q4 * H_ + e] : 0.f;

        if (tid < 40) ((unsigned*)&hs[0][0])[tid] = 0;   // h(-1) = 0
        __syncthreads();

        float cold = 0.f;
        _Float16 h16 = (_Float16)0.f;
        int par = 0;

// 40 f16x2 dots (builtin fdot2 = proven numerics) + 4-lane distribute-reduce:
// lane q4 ends with the 4-slice total of gate q4 in S.
#define DOTS_REDUCE(VPBASE)                                                          \
    h4 v0 = (VPBASE)[0], v1 = (VPBASE)[1], v2 = (VPBASE)[2], v3 = (VPBASE)[3],       \
       v4 = (VPBASE)[4];                                                             \
    h2 p0 = lo2(v0), p1 = hi2(v0), p2 = lo2(v1), p3 = hi2(v1), p4 = lo2(v2);         \
    h2 p5 = hi2(v2), p6 = lo2(v3), p7 = hi2(v3), p8 = lo2(v4), p9 = hi2(v4);         \
    float aI = 0.f, aF = 0.f, aG = 0.f, aO = 0.f;                                    \
    aI = __builtin_amdgcn_fdot2(bc(W0.x), p0, aI, false);                            \
    aI = __builtin_amdgcn_fdot2(bc(W0.y), p1, aI, false);                            \
    aI = __builtin_amdgcn_fdot2(bc(W0.z), p2, aI, false);                            \
    aI = __builtin_amdgcn_fdot2(bc(W0.w), p3, aI, false);                            \
    aI = __builtin_amdgcn_fdot2(bc(W1.x), p4, aI, false);                            \
    aI = __builtin_amdgcn_fdot2(bc(W1.y), p5, aI, false);                            \
    aI = __builtin_amdgcn_fdot2(bc(W1.z), p6, aI, false);                            \
    aI = __builtin_amdgcn_fdot2(bc(W1.w), p7, aI, false);                            \
    aI = __builtin_amdgcn_fdot2(bc(W2.x), p8, aI, false);                            \
    aI = __builtin_amdgcn_fdot2(bc(W2.y), p9, aI, false);                            \
    aF = __builtin_amdgcn_fdot2(bc(W2.z), p0, aF, false);                            \
    aF = __builtin_amdgcn_fdot2(bc(W2.w), p1, aF, false);                            \
    aF = __builtin_amdgcn_fdot2(bc(W3.x), p2, aF, false);                            \
    aF = __builtin_amdgcn_fdot2(bc(W3.y), p3, aF, false);                            \
    aF = __builtin_amdgcn_fdot2(bc(W3.z), p4, aF, false);                            \
    aF = __builtin_amdgcn_fdot2(bc(W3.w), p5, aF, false);                            \
    aF = __builtin_amdgcn_fdot2(bc(W4.x), p6, aF, false);                            \
    aF = __builtin_amdgcn_fdot2(bc(W4.y), p7, aF, false);                            \
    aF = __builtin_amdgcn_fdot2(bc(W4.z), p8, aF, false);                            \
    aF = __builtin_amdgcn_fdot2(bc(W4.w), p9, aF, false);                            \
    aG = __builtin_amdgcn_fdot2(bc(W5.x), p0, aG, false);                            \
    aG = __builtin_amdgcn_fdot2(bc(W5.y), p1, aG, false);                            \
    aG = __builtin_amdgcn_fdot2(bc(W5.z), p2, aG, false);                            \
    aG = __builtin_amdgcn_fdot2(bc(W5.w), p3, aG, false);                            \
    aG = __builtin_amdgcn_fdot2(bc(W6.x), p4, aG, false);                            \
    aG = __builtin_amdgcn_fdot2(bc(W6.y), p5, aG, false);                            \
    aG = __builtin_amdgcn_fdot2(bc(W6.z), p6, aG, false);                            \
    aG = __builtin_amdgcn_fdot2(bc(W6.w), p7, aG, false);                            \
    aG = __builtin_amdgcn_fdot2(bc(W7.x), p8, aG, false);                            \
    aG = __builtin_amdgcn_fdot2(bc(W7.y), p9, aG, false);                            \
    aO = __builtin_amdgcn_fdot2(bc(W7.z), p0, aO, false);                            \
    aO = __builtin_amdgcn_fdot2(bc(W7.w), p1, aO, false);                            \
    aO = __builtin_amdgcn_fdot2(bc(W8.x), p2, aO, false);                            \
    aO = __builtin_amdgcn_fdot2(bc(W8.y), p3, aO, false);                            \
    aO = __builtin_amdgcn_fdot2(bc(W8.z), p4, aO, false);                            \
    aO = __builtin_amdgcn_fdot2(bc(W8.w), p5, aO, false);                            \
    aO = __builtin_amdgcn_fdot2(bc(W9.x), p6, aO, false);                            \
    aO = __builtin_amdgcn_fdot2(bc(W9.y), p7, aO, false);                            \
    aO = __builtin_amdgcn_fdot2(bc(W9.z), p8, aO, false);                            \
    aO = __builtin_amdgcn_fdot2(bc(W9.w), p9, aO, false);                            \
    float kI = sel1 ? aF : aI, oI = sel1 ? aI : aF;                                  \
    float AIF = kI + dpp_mov<0xB1>(oI);                                              \
    float kG = sel1 ? aO : aG, oG = sel1 ? aG : aO;                                  \
    float BGO = kG + dpp_mov<0xB1>(oG);                                              \
    float k2v = sel2 ? BGO : AIF, o2 = sel2 ? AIF : BGO;                             \
    float S = k2v + dpp_mov<0x4E>(o2);

#define PRODUCE(TP) {                                                                \
    const h4* vp = (const h4*)(&hist[TP][0] + 20 * q4);                              \
    DOTS_REDUCE(vp)                                                                  \
    xp[(TP) & 3][q4][e] = S + bias;                                                  \
}

        // ---- prologue: producers fill xp for t = 0..LAG-1 ----
        for (int pp = 0; pp < LAG; ++pp) {
            if (isProd) { PRODUCE(pp) }
            __syncthreads();
        }

        // ---- main scan: chain consumes xp[t] while producers build xp[t+LAG] ----
#pragma unroll 2
        for (int t = 0; t < T_; ++t) {
            if (isProd) {
                int tp = t + LAG;
                if (tp < T_) { PRODUCE(tp) }
            } else {
                const h4* vp = (const h4*)(&hs[par][0] + 20 * q4);
                if (t && q4 == 1) hist[t - 1][e] = h16;   // deferred history write
                DOTS_REDUCE(vp)
                S += xp[t & 3][q4][e];                    // x-projection + bias

                float y   = __builtin_amdgcn_rcpf(1.f + __builtin_amdgcn_exp2f(mA * S));
                float act = __builtin_fmaf(bA, y, cA0);   // lane's own gate only
                float t2v  = dpp_mov<0x4E>(act);          // i<-g, f<-o
                float prod = act * t2v;                   // i-lane: i*g
                float t3v  = dpp_mov<0xB1>(prod);         // f-lane receives i*g
                float cnew = __builtin_fmaf(act, cold, t3v);
                float th   = __builtin_fmaf(2.f,
                               __builtin_amdgcn_rcpf(1.f + __builtin_amdgcn_exp2f(-2.885390082f * cnew)),
                               -1.f);
                float h = t2v * th;                       // f-lane: o * tanh(c)
                h16 = (_Float16)h;
                cold = cnew;
                if (q4 == 1) hs[par ^ 1][e] = h16;
            }
            __syncthreads();
            par ^= 1;
        }
        if (!isProd && q4 == 1) hist[T_ - 1][e] = h16;    // flush last step
        __syncthreads();
#undef PRODUCE
#undef DOTS_REDUCE
    }

    // ---- fc on final hidden state ----
    if (tid < NC_) {
        float acc = fcb[tid];
#pragma unroll
        for (int j = 0; j < H_; ++j) acc += fcw[tid * H_ + j] * (float)hist[T_ - 1][j];
        out[b * NC_ + tid] = acc;
    }
}

extern "C" void kernel_launch(void* const* d_in, const int* in_sizes, int n_in,
                              void* d_out, int out_size, void* d_ws, size_t ws_size,
                              hipStream_t stream) {
    const float* x    = (const float*)d_in[0];
    const float* Wih0 = (const float*)d_in[1];
    const float* WihR = (const float*)d_in[2];
    const float* Whh  = (const float*)d_in[3];
    const float* bih  = (const float*)d_in[4];
    const float* bhh  = (const float*)d_in[5];
    const float* fcw  = (const float*)d_in[6];
    const float* fcb  = (const float*)d_in[7];

    unsigned* w1 = (unsigned*)d_ws;           // 128000 dwords
    unsigned* w2 = w1 + 128000;               // 128000 dwords
    float* bbuf  = (float*)(w2 + 128000);     // 3200 floats

    prep_kernel<<<dim3(500), dim3(256), 0, stream>>>(
        Wih0, WihR, Whh, bih, bhh, w1, w2, bbuf);

    lstm_stack_kernel<<<dim3(B_), dim3(TPB), 0, stream>>>(
        x, (const uint4*)w1, (const uint4*)w2, bbuf, fcw, fcb, (float*)d_out);
}

// Round 16
// 2424.927 us; speedup vs baseline: 1.1781x; 1.0172x over previous
//
#include <hip/hip_runtime.h>

#define B_   256
#define T_   512
#define IN_  34
#define H_   80
#define L_   10
#define NC_  5
#define G4   320
#define TPB  640        // waves 0-4: serial chain (h-side); waves 5-9: xp producers (x-side)
#define HPS  96         // hist row: 4 slices x 24 f16 (20 used + 4 pad) = 48B-aligned slices
#define LAG  2          // producer lead (timesteps)

typedef _Float16 h2 __attribute__((ext_vector_type(2)));

template <int CTRL>
__device__ __forceinline__ float dpp_mov(float v) {
    return __int_as_float(__builtin_amdgcn_update_dpp(0, __float_as_int(v), CTRL, 0xF, 0xF, true));
}
__device__ __forceinline__ h2 bc(unsigned u) { return __builtin_bit_cast(h2, u); }

// Weight layouts identical to R14 (proven): lane = e*4 + q4 owns, for all 4 gates,
// K-slice [20*q4, 20*q4+20) (x-side w1, h-side w2) of row gate*80+e.
__global__ void prep_kernel(const float* __restrict__ Wih0, const float* __restrict__ WihR,
                            const float* __restrict__ Whh,  const float* __restrict__ bih,
                            const float* __restrict__ bhh,
                            unsigned* __restrict__ w1, unsigned* __restrict__ w2,
                            float* __restrict__ bbuf) {
    int idx = blockIdx.x * 256 + threadIdx.x;          // dword index
    const int ND = L_ * 10 * G4 * 4;                   // 128000 dwords per half
    if (idx < ND) {
        int c    = idx & 3;
        int lane = (idx >> 2) % G4;
        int n    = ((idx >> 2) / G4) % 10;
        int l    = (idx >> 2) / (G4 * 10);
        int j = n * 4 + c;
        int gate = j / 10, q = j % 10;
        int e = lane >> 2, q4 = lane & 3;
        int row = gate * H_ + e;
        int k0 = 20 * q4 + 2 * q;
        float a, b;
        if (l == 0) {
            a = (k0     < IN_) ? Wih0[row * IN_ + k0]     : 0.f;
            b = (k0 + 1 < IN_) ? Wih0[row * IN_ + k0 + 1] : 0.f;
        } else {
            const float* p = WihR + ((size_t)(l - 1) * G4 + row) * H_;
            a = p[k0]; b = p[k0 + 1];
        }
        h2 pa; pa[0] = (_Float16)a; pa[1] = (_Float16)b;
        w1[idx] = __builtin_bit_cast(unsigned, pa);
        const float* ph = Whh + ((size_t)l * G4 + row) * H_;
        h2 pb; pb[0] = (_Float16)ph[k0]; pb[1] = (_Float16)ph[k0 + 1];
        w2[idx] = __builtin_bit_cast(unsigned, pb);
    }
    if (idx < L_ * G4) bbuf[idx] = bih[idx] + bhh[idx];
}

__global__ __launch_bounds__(TPB, 1) void lstm_stack_kernel(
    const float* __restrict__ x,      // [B,T,34]
    const uint4* __restrict__ w1,     // x-side weights (producers)
    const uint4* __restrict__ w2,     // h-side weights (chain)
    const float* __restrict__ bbuf,   // [10][320]
    const float* __restrict__ fcw,    // [5,80]
    const float* __restrict__ fcb,    // [5]
    float* __restrict__ out)          // [B,5]
{
    const int b    = blockIdx.x;
    const int tid  = threadIdx.x;             // 0..639
    const bool isProd = tid >= G4;            // waves 5-9 produce xp
    const int lane = isProd ? tid - G4 : tid; // 0..319
    const int e    = lane >> 2;               // h element 0..79
    const int q4   = lane & 3;                // K-slice id == final gate id (0=i 1=f 2=g 3=o)
    const int eS   = (e / 20) * 24 + (e % 20);  // sliced column for element e

    // chain waves get scheduler priority: their serial path gates every step
    if (!isProd) __builtin_amdgcn_s_setprio(1);

    const float mA  = (q4 == 2) ? -2.885390082f : -1.442695041f;
    const float bA  = (q4 == 2) ? 2.f : 1.f;
    const float cA0 = (q4 == 2) ? -1.f : 0.f;
    const bool  sel1 = (q4 & 1) != 0;
    const bool  sel2 = (q4 & 2) != 0;

    __shared__ __align__(16) _Float16 hist[T_][HPS];  // 96 KB: x (f16) then h history, sliced rows
    __shared__ __align__(16) float xp[4][4][84];      // 5.4 KB ring: [slot][gate][e]
    __shared__ __align__(16) _Float16 hs[2][4][24];   // h(t-1) ping-pong, sliced

    // ---- stage x -> f16 hist (zero-pad 34..79); slice pads never read ----
    for (int j = tid; j < T_ * H_; j += TPB) {
        int t = j / H_, k = j % H_;
        float v = (k < IN_) ? x[((size_t)b * T_ + t) * IN_ + k] : 0.f;
        hist[t][(k / 20) * 24 + (k % 20)] = (_Float16)v;
    }

    for (int l = 0; l < L_; ++l) {
        // ---- this lane's 40-dword weight half (proven-resident size) ----
        const uint4* wp = (isProd ? w1 : w2) + (size_t)l * 10 * G4 + lane;
        uint4 W0 = wp[0 * G4], W1 = wp[1 * G4], W2 = wp[2 * G4], W3 = wp[3 * G4], W4 = wp[4 * G4];
        uint4 W5 = wp[5 * G4], W6 = wp[6 * G4], W7 = wp[7 * G4], W8 = wp[8 * G4], W9 = wp[9 * G4];
        const float bias = isProd ? bbuf[l * G4 + q4 * H_ + e] : 0.f;

        if (tid < 96) ((unsigned*)hs)[tid] = 0;   // h(-1) = 0 (both buffers)
        __syncthreads();

        float cold = 0.f;
        _Float16 h16 = (_Float16)0.f;
        int par = 0;

// 3 aligned LDS loads (b128+b128+b64) + 40 f16x2 dots (builtin fdot2 numerics) +
// 4-lane distribute-reduce: lane q4 ends with the 4-slice total of gate q4 in S.
#define DOTS_REDUCE(SLICEBASE)                                                       \
    const uint4* vba_ = (const uint4*)(SLICEBASE);                                   \
    uint4 LA_ = vba_[0], LB_ = vba_[1];                                              \
    uint2 LC_ = *(const uint2*)((const char*)(SLICEBASE) + 32);                      \
    h2 p0 = bc(LA_.x), p1 = bc(LA_.y), p2 = bc(LA_.z), p3 = bc(LA_.w);               \
    h2 p4 = bc(LB_.x), p5 = bc(LB_.y), p6 = bc(LB_.z), p7 = bc(LB_.w);               \
    h2 p8 = bc(LC_.x), p9 = bc(LC_.y);                                               \
    float aI = 0.f, aF = 0.f, aG = 0.f, aO = 0.f;                                    \
    aI = __builtin_amdgcn_fdot2(bc(W0.x), p0, aI, false);                            \
    aI = __builtin_amdgcn_fdot2(bc(W0.y), p1, aI, false);                            \
    aI = __builtin_amdgcn_fdot2(bc(W0.z), p2, aI, false);                            \
    aI = __builtin_amdgcn_fdot2(bc(W0.w), p3, aI, false);                            \
    aI = __builtin_amdgcn_fdot2(bc(W1.x), p4, aI, false);                            \
    aI = __builtin_amdgcn_fdot2(bc(W1.y), p5, aI, false);                            \
    aI = __builtin_amdgcn_fdot2(bc(W1.z), p6, aI, false);                            \
    aI = __builtin_amdgcn_fdot2(bc(W1.w), p7, aI, false);                            \
    aI = __builtin_amdgcn_fdot2(bc(W2.x), p8, aI, false);                            \
    aI = __builtin_amdgcn_fdot2(bc(W2.y), p9, aI, false);                            \
    aF = __builtin_amdgcn_fdot2(bc(W2.z), p0, aF, false);                            \
    aF = __builtin_amdgcn_fdot2(bc(W2.w), p1, aF, false);                            \
    aF = __builtin_amdgcn_fdot2(bc(W3.x), p2, aF, false);                            \
    aF = __builtin_amdgcn_fdot2(bc(W3.y), p3, aF, false);                            \
    aF = __builtin_amdgcn_fdot2(bc(W3.z), p4, aF, false);                            \
    aF = __builtin_amdgcn_fdot2(bc(W3.w), p5, aF, false);                            \
    aF = __builtin_amdgcn_fdot2(bc(W4.x), p6, aF, false);                            \
    aF = __builtin_amdgcn_fdot2(bc(W4.y), p7, aF, false);                            \
    aF = __builtin_amdgcn_fdot2(bc(W4.z), p8, aF, false);                            \
    aF = __builtin_amdgcn_fdot2(bc(W4.w), p9, aF, false);                            \
    aG = __builtin_amdgcn_fdot2(bc(W5.x), p0, aG, false);                            \
    aG = __builtin_amdgcn_fdot2(bc(W5.y), p1, aG, false);                            \
    aG = __builtin_amdgcn_fdot2(bc(W5.z), p2, aG, false);                            \
    aG = __builtin_amdgcn_fdot2(bc(W5.w), p3, aG, false);                            \
    aG = __builtin_amdgcn_fdot2(bc(W6.x), p4, aG, false);                            \
    aG = __builtin_amdgcn_fdot2(bc(W6.y), p5, aG, false);                            \
    aG = __builtin_amdgcn_fdot2(bc(W6.z), p6, aG, false);                            \
    aG = __builtin_amdgcn_fdot2(bc(W6.w), p7, aG, false);                            \
    aG = __builtin_amdgcn_fdot2(bc(W7.x), p8, aG, false);                            \
    aG = __builtin_amdgcn_fdot2(bc(W7.y), p9, aG, false);                            \
    aO = __builtin_amdgcn_fdot2(bc(W7.z), p0, aO, false);                            \
    aO = __builtin_amdgcn_fdot2(bc(W7.w), p1, aO, false);                            \
    aO = __builtin_amdgcn_fdot2(bc(W8.x), p2, aO, false);                            \
    aO = __builtin_amdgcn_fdot2(bc(W8.y), p3, aO, false);                            \
    aO = __builtin_amdgcn_fdot2(bc(W8.z), p4, aO, false);                            \
    aO = __builtin_amdgcn_fdot2(bc(W8.w), p5, aO, false);                            \
    aO = __builtin_amdgcn_fdot2(bc(W9.x), p6, aO, false);                            \
    aO = __builtin_amdgcn_fdot2(bc(W9.y), p7, aO, false);                            \
    aO = __builtin_amdgcn_fdot2(bc(W9.z), p8, aO, false);                            \
    aO = __builtin_amdgcn_fdot2(bc(W9.w), p9, aO, false);                            \
    float kI = sel1 ? aF : aI, oI = sel1 ? aI : aF;                                  \
    float AIF = kI + dpp_mov<0xB1>(oI);                                              \
    float kG = sel1 ? aO : aG, oG = sel1 ? aG : aO;                                  \
    float BGO = kG + dpp_mov<0xB1>(oG);                                              \
    float k2v = sel2 ? BGO : AIF, o2 = sel2 ? AIF : BGO;                             \
    float S = k2v + dpp_mov<0x4E>(o2);

#define PRODUCE(TP) {                                                                \
    DOTS_REDUCE(&hist[TP][q4 * 24])                                                  \
    xp[(TP) & 3][q4][e] = S + bias;                                                  \
}

        // ---- prologue: producers fill xp for t = 0..LAG-1 ----
        for (int pp = 0; pp < LAG; ++pp) {
            if (isProd) { PRODUCE(pp) }
            __syncthreads();
        }

        // ---- main scan: chain consumes xp[t] while producers build xp[t+LAG] ----
#pragma unroll 2
        for (int t = 0; t < T_; ++t) {
            if (isProd) {
                int tp = t + LAG;
                if (tp < T_) { PRODUCE(tp) }
            } else {
                if (t && q4 == 1) hist[t - 1][eS] = h16;   // deferred history write
                DOTS_REDUCE(&hs[par][q4][0])
                S += xp[t & 3][q4][e];                     // x-projection + bias

                float y   = __builtin_amdgcn_rcpf(1.f + __builtin_amdgcn_exp2f(mA * S));
                float act = __builtin_fmaf(bA, y, cA0);    // lane's own gate only
                float t2v  = dpp_mov<0x4E>(act);           // i<-g, f<-o
                float prod = act * t2v;                    // i-lane: i*g
                float t3v  = dpp_mov<0xB1>(prod);          // f-lane receives i*g
                float cnew = __builtin_fmaf(act, cold, t3v);
                float th   = __builtin_fmaf(2.f,
                               __builtin_amdgcn_rcpf(1.f + __builtin_amdgcn_exp2f(-2.885390082f * cnew)),
                               -1.f);
                float h = t2v * th;                        // f-lane: o * tanh(c)
                h16 = (_Float16)h;
                cold = cnew;
                if (q4 == 1) hs[par ^ 1][0][eS] = h16;
            }
            __syncthreads();
            par ^= 1;
        }
        if (!isProd && q4 == 1) hist[T_ - 1][eS] = h16;    // flush last step
        __syncthreads();
#undef PRODUCE
#undef DOTS_REDUCE
    }

    // ---- fc on final hidden state ----
    if (tid < NC_) {
        float acc = fcb[tid];
#pragma unroll
        for (int j = 0; j < H_; ++j)
            acc += fcw[tid * H_ + j] * (float)hist[T_ - 1][(j / 20) * 24 + (j % 20)];
        out[b * NC_ + tid] = acc;
    }
}

extern "C" void kernel_launch(void* const* d_in, const int* in_sizes, int n_in,
                              void* d_out, int out_size, void* d_ws, size_t ws_size,
                              hipStream_t stream) {
    const float* x    = (const float*)d_in[0];
    const float* Wih0 = (const float*)d_in[1];
    const float* WihR = (const float*)d_in[2];
    const float* Whh  = (const float*)d_in[3];
    const float* bih  = (const float*)d_in[4];
    const float* bhh  = (const float*)d_in[5];
    const float* fcw  = (const float*)d_in[6];
    const float* fcb  = (const float*)d_in[7];

    unsigned* w1 = (unsigned*)d_ws;           // 128000 dwords
    unsigned* w2 = w1 + 128000;               // 128000 dwords
    float* bbuf  = (float*)(w2 + 128000);     // 3200 floats

    prep_kernel<<<dim3(500), dim3(256), 0, stream>>>(
        Wih0, WihR, Whh, bih, bhh, w1, w2, bbuf);

    lstm_stack_kernel<<<dim3(B_), dim3(TPB), 0, stream>>>(
        x, (const uint4*)w1, (const uint4*)w2, bbuf, fcw, fcb, (float*)d_out);
}